// Round 9
// baseline (988.212 us; speedup 1.0000x reference)
//
#include <hip/hip_runtime.h>

#define NN 50000
#define NP 50048    // padded rows for direct tail reads
#define NMT32 1563  // cdiv(NN,32)
#define NE 800000
#define EP (NE + NN)
#define DEMB 128
#define DHID 512
#define NB_SCAN 196  // cdiv(NN,256)
#define HSTR 520     // hid LDS stride (ushorts): 16B-aligned rows, 2-way banks

typedef unsigned short ushort_t;
typedef __attribute__((ext_vector_type(8))) short short8_t;
typedef __attribute__((ext_vector_type(4))) float float4_t;

__device__ __forceinline__ float bf2f(ushort_t u) {
    return __uint_as_float(((unsigned int)u) << 16);
}
__device__ __forceinline__ ushort_t f2bf(float f) {
    unsigned int x = __float_as_uint(f);
    x += 0x7fffu + ((x >> 16) & 1u);
    return (ushort_t)(x >> 16);
}
__device__ __forceinline__ float lo16(unsigned int w) { return __uint_as_float(w << 16); }
__device__ __forceinline__ float hi16(unsigned int w) { return __uint_as_float(w & 0xffff0000u); }
__device__ __forceinline__ unsigned int pack2(float a, float b) {
    return (unsigned int)f2bf(a) | ((unsigned int)f2bf(b) << 16);
}
static inline int cdiv(int a, int b) { return (a + b - 1) / b; }

// ---------------- dtype detect + batched convert ----------------
__global__ void k_detect(const unsigned int* __restrict__ Jw, int* __restrict__ flag) {
    if (threadIdx.x != 0 || blockIdx.x != 0) return;
    int votes = 0;
    for (int i = 0; i < 8; ++i) {
        unsigned int w = Jw[i];
        unsigned int ex = (w >> 23) & 0xFFu;
        if ((w >> 31) == 0u && ex >= 100u && ex <= 126u) votes++;
    }
    *flag = (votes >= 6) ? 1 : 0;
}

struct CvtArgs {
    const void* src[16];
    float* dst[16];
    int n[16];
};
__global__ void k_cvt_all(CvtArgs a, const int* __restrict__ flag) {
    int which = blockIdx.y;
    int i = blockIdx.x * 256 + threadIdx.x;
    if (i >= a.n[which]) return;
    float v;
    if (*flag) v = ((const float*)a.src[which])[i];
    else       v = bf2f(((const ushort_t*)a.src[which])[i]);
    a.dst[which][i] = v;
}

struct TrArgs {
    const float* src[6];
    ushort_t* dst[6];
    int K[6];
    int Nc[6];
};
__global__ void k_tr_all(TrArgs a) {
    int which = blockIdx.y;
    int idx = blockIdx.x * 256 + threadIdx.x;
    int K = a.K[which], Nc = a.Nc[which];
    if (idx >= K * Nc) return;
    int k = idx / Nc, n = idx - k * Nc;
    a.dst[which][n * K + k] = f2bf(a.src[which][idx]);
}

// ---------------- CSR build ----------------
__global__ void k_deg(const int* __restrict__ ei, int* __restrict__ deg) {
    int e = blockIdx.x * 256 + threadIdx.x;
    if (e >= EP) return;
    int d = (e < NE) ? ei[NE + e] : (e - NE);
    atomicAdd(&deg[d], 1);
}

__global__ void k_part(const int* __restrict__ deg, int* __restrict__ part) {
    __shared__ int sm[256];
    int i = blockIdx.x * 256 + threadIdx.x;
    int v = (i < NN) ? deg[i] : 0;
    sm[threadIdx.x] = v;
    __syncthreads();
    for (int off = 128; off > 0; off >>= 1) {
        if (threadIdx.x < off) sm[threadIdx.x] += sm[threadIdx.x + off];
        __syncthreads();
    }
    if (threadIdx.x == 0) part[blockIdx.x] = sm[0];
}

__global__ void k_scan2(const int* __restrict__ part, int* __restrict__ poff,
                        int* __restrict__ rowp) {
    __shared__ int sm[256];
    int t = threadIdx.x;
    int v = (t < NB_SCAN) ? part[t] : 0;
    sm[t] = v;
    __syncthreads();
    int incl = v;
    for (int off = 1; off < 256; off <<= 1) {
        int u = (t >= off) ? sm[t - off] : 0;
        __syncthreads();
        incl += u;
        sm[t] = incl;
        __syncthreads();
    }
    if (t < NB_SCAN) poff[t] = incl - v;
    if (t == 255) rowp[NN] = sm[255];
}

// rowp + dinv + fill-init fused
__global__ void k_rowp(const int* __restrict__ deg, const int* __restrict__ poff,
                       int* __restrict__ rowp, float* __restrict__ dinv,
                       int* __restrict__ fill) {
    __shared__ int sm[256];
    int i = blockIdx.x * 256 + threadIdx.x;
    int t = threadIdx.x;
    int v = (i < NN) ? deg[i] : 0;
    sm[t] = v;
    __syncthreads();
    int incl = v;
    for (int off = 1; off < 256; off <<= 1) {
        int u = (t >= off) ? sm[t - off] : 0;
        __syncthreads();
        incl += u;
        sm[t] = incl;
        __syncthreads();
    }
    if (i < NN) {
        int rp = poff[blockIdx.x] + incl - v;
        rowp[i] = rp;
        fill[i] = rp;
        dinv[i] = rsqrtf(fmaxf((float)v, 1.0f));
    }
}

__global__ void k_fill(const int* __restrict__ ei, int* __restrict__ fillpos,
                       ushort_t* __restrict__ col) {
    int e = blockIdx.x * 256 + threadIdx.x;
    if (e >= EP) return;
    int s, d;
    if (e < NE) { s = ei[e]; d = ei[NE + e]; } else { s = d = e - NE; }
    int pos = atomicAdd(&fillpos[d], 1);
    col[pos] = (ushort_t)s;
}

// ---------------- elementwise ----------------
__global__ void k_lin0(const float* __restrict__ x, const float* __restrict__ J,
                       const float* __restrict__ w, const float* __restrict__ b,
                       float* __restrict__ h, ushort_t* __restrict__ hB) {
    int idx = blockIdx.x * 256 + threadIdx.x;
    if (idx >= NN * DEMB) return;
    int n = idx >> 7, d = idx & 127;
    float v = x[n * 2] * w[d] + x[n * 2 + 1] * w[DEMB + d] + J[n] * w[2 * DEMB + d] + b[d];
    h[idx] = v;
    hB[idx] = f2bf(v);
}

__global__ void k_att(const unsigned int* __restrict__ xlB, const float* __restrict__ asrc,
                      const float* __restrict__ adst, float* __restrict__ a_s,
                      float* __restrict__ a_d) {
    int idx = blockIdx.x * 256 + threadIdx.x;
    if (idx >= NN * 8) return;
    int n = idx >> 3, hh = idx & 7;
    const unsigned int* row = xlB + (size_t)n * 64 + hh * 8;
    float s = 0.f, d = 0.f;
#pragma unroll
    for (int c = 0; c < 8; ++c) {
        unsigned int w = row[c];
        float v0 = lo16(w), v1 = hi16(w);
        s += v0 * asrc[hh * 16 + 2 * c] + v1 * asrc[hh * 16 + 2 * c + 1];
        d += v0 * adst[hh * 16 + 2 * c] + v1 * adst[hh * 16 + 2 * c + 1];
    }
    a_s[idx] = s;
    a_d[idx] = d;
}

// BN1 stats pass: recompute z = h + g@w1, accumulate stats only
__global__ __launch_bounds__(256) void k_z1s(const float* __restrict__ h, const float* __restrict__ g,
                                             const float* __restrict__ w1,
                                             float* __restrict__ stats) {
    int d = threadIdx.x & 127;
    int rstart = blockIdx.x * 2 + (threadIdx.x >> 7);
    int stride = gridDim.x * 2;
    float s1 = 0.f, s2 = 0.f;
    for (int r = rstart; r < NN; r += stride) {
        const float* gr = g + r * 16;
        float s = h[(size_t)r * DEMB + d];
#pragma unroll
        for (int c = 0; c < 16; ++c) s += gr[c] * w1[c * DEMB + d];
        s1 += s;
        s2 += s * s;
    }
    __shared__ float b1[256], b2[256];
    b1[threadIdx.x] = s1;
    b2[threadIdx.x] = s2;
    __syncthreads();
    if (threadIdx.x < 128) {
        atomicAdd(&stats[threadIdx.x], b1[threadIdx.x] + b1[threadIdx.x + 128]);
        atomicAdd(&stats[128 + threadIdx.x], b2[threadIdx.x] + b2[threadIdx.x + 128]);
    }
}

// BN1 apply with recompute
__global__ void k_bnapply1(const float* __restrict__ h, const float* __restrict__ g,
                           const float* __restrict__ w1, const float* __restrict__ stats,
                           const float* __restrict__ gam, const float* __restrict__ bet,
                           float* __restrict__ outF, ushort_t* __restrict__ outB) {
    int idx = blockIdx.x * 256 + threadIdx.x;
    if (idx >= NN * DEMB) return;
    int n = idx >> 7, d = idx & 127;
    float s = h[idx];
    const float* gr = g + n * 16;
#pragma unroll
    for (int c = 0; c < 16; ++c) s += gr[c] * w1[c * DEMB + d];
    const float invN = 1.0f / (float)NN;
    float mu = stats[d] * invN;
    float var = stats[128 + d] * invN - mu * mu;
    float rs = rsqrtf(fmaxf(var, 0.f) + 1e-5f);
    float v = gam[d] * (s - mu) * rs + bet[d];
    outF[idx] = v;
    outB[idx] = f2bf(v);
}

// BN2 apply (layer 0)
__global__ void k_bnapply(const float* __restrict__ z, const float* __restrict__ stats,
                          const float* __restrict__ gam, const float* __restrict__ bet,
                          float* __restrict__ outF, ushort_t* __restrict__ outB) {
    int idx = blockIdx.x * 256 + threadIdx.x;
    if (idx >= NN * DEMB) return;
    int d = idx & 127;
    const float invN = 1.0f / (float)NN;
    float mu = stats[d] * invN;
    float var = stats[128 + d] * invN - mu * mu;
    float rs = rsqrtf(fmaxf(var, 0.f) + 1e-5f);
    float v = gam[d] * (z[idx] - mu) * rs + bet[d];
    outF[idx] = v;
    outB[idx] = f2bf(v);
}

// BN2 apply (layer 1, final): emit APPNP inputs directly
__global__ void k_bnapply_fin(const float* __restrict__ z, const float* __restrict__ stats,
                              const float* __restrict__ gam, const float* __restrict__ bet,
                              const float* __restrict__ dinv,
                              unsigned int* __restrict__ hs, unsigned int* __restrict__ h0p) {
    int idx = blockIdx.x * 256 + threadIdx.x;
    if (idx >= NN * 64) return;
    int n = idx >> 6, d0 = (idx & 63) * 2;
    const float invN = 1.0f / (float)NN;
    float2 zv = ((const float2*)z)[idx];
    float mu0 = stats[d0] * invN, mu1 = stats[d0 + 1] * invN;
    float v0 = stats[128 + d0] * invN - mu0 * mu0;
    float v1 = stats[128 + d0 + 1] * invN - mu1 * mu1;
    float rs0 = rsqrtf(fmaxf(v0, 0.f) + 1e-5f);
    float rs1 = rsqrtf(fmaxf(v1, 0.f) + 1e-5f);
    float a = gam[d0] * (zv.x - mu0) * rs0 + bet[d0];
    float b = gam[d0 + 1] * (zv.y - mu1) * rs1 + bet[d0 + 1];
    float di = dinv[n];
    hs[idx] = pack2(di * a, di * b);
    h0p[idx] = pack2(a, b);
}

// ---------------- GAT: single-pass softmax-aggregate (wave per node) ----------------
__global__ __launch_bounds__(256) void k_gat(const int* __restrict__ rowp,
                                             const ushort_t* __restrict__ col,
                                             const float* __restrict__ a_s, const float* __restrict__ a_d,
                                             const unsigned int* __restrict__ xlB, float* __restrict__ g) {
    int wid = (blockIdx.x * 256 + threadIdx.x) >> 6;
    int lane = threadIdx.x & 63;
    if (wid >= NN) return;
    int p0 = rowp[wid], p1 = rowp[wid + 1];
    int hh = lane >> 3;
    float ad2 = a_d[wid * 8 + hh];
    float acc0 = 0.f, acc1 = 0.f, s = 0.f;
    int p = p0;
    while (p < p1) {
        int cnt = p1 - p;
        if (cnt > 64) cnt = 64;
        int pl = p + lane;
        int jv = (int)col[pl < p1 ? pl : (p1 - 1)];
        int i = 0;
        for (; i + 8 <= cnt; i += 8) {
            int j0 = __shfl(jv, i),     j1 = __shfl(jv, i + 1);
            int j2 = __shfl(jv, i + 2), j3 = __shfl(jv, i + 3);
            int j4 = __shfl(jv, i + 4), j5 = __shfl(jv, i + 5);
            int j6 = __shfl(jv, i + 6), j7 = __shfl(jv, i + 7);
            float e0 = a_s[j0 * 8 + hh] + ad2, e1 = a_s[j1 * 8 + hh] + ad2;
            float e2 = a_s[j2 * 8 + hh] + ad2, e3 = a_s[j3 * 8 + hh] + ad2;
            float e4 = a_s[j4 * 8 + hh] + ad2, e5 = a_s[j5 * 8 + hh] + ad2;
            float e6 = a_s[j6 * 8 + hh] + ad2, e7 = a_s[j7 * 8 + hh] + ad2;
            unsigned int w0 = xlB[j0 * 64 + lane], w1 = xlB[j1 * 64 + lane];
            unsigned int w2 = xlB[j2 * 64 + lane], w3 = xlB[j3 * 64 + lane];
            unsigned int w4 = xlB[j4 * 64 + lane], w5 = xlB[j5 * 64 + lane];
            unsigned int w6 = xlB[j6 * 64 + lane], w7 = xlB[j7 * 64 + lane];
            e0 = e0 > 0.f ? e0 : 0.2f * e0;  e1 = e1 > 0.f ? e1 : 0.2f * e1;
            e2 = e2 > 0.f ? e2 : 0.2f * e2;  e3 = e3 > 0.f ? e3 : 0.2f * e3;
            e4 = e4 > 0.f ? e4 : 0.2f * e4;  e5 = e5 > 0.f ? e5 : 0.2f * e5;
            e6 = e6 > 0.f ? e6 : 0.2f * e6;  e7 = e7 > 0.f ? e7 : 0.2f * e7;
            float al0 = __expf(e0), al1 = __expf(e1), al2 = __expf(e2), al3 = __expf(e3);
            float al4 = __expf(e4), al5 = __expf(e5), al6 = __expf(e6), al7 = __expf(e7);
            s += al0 + al1 + al2 + al3 + al4 + al5 + al6 + al7;
            acc0 += al0 * lo16(w0) + al1 * lo16(w1) + al2 * lo16(w2) + al3 * lo16(w3) +
                    al4 * lo16(w4) + al5 * lo16(w5) + al6 * lo16(w6) + al7 * lo16(w7);
            acc1 += al0 * hi16(w0) + al1 * hi16(w1) + al2 * hi16(w2) + al3 * hi16(w3) +
                    al4 * hi16(w4) + al5 * hi16(w5) + al6 * hi16(w6) + al7 * hi16(w7);
        }
        for (; i < cnt; ++i) {
            int j = __shfl(jv, i);
            float e = a_s[j * 8 + hh] + ad2;
            e = e > 0.f ? e : 0.2f * e;
            float al = __expf(e);
            unsigned int w = xlB[j * 64 + lane];
            s += al;
            acc0 += al * lo16(w);
            acc1 += al * hi16(w);
        }
        p += cnt;
    }
    float inv = 1.f / s;
    acc0 *= inv;
    acc1 *= inv;
    acc0 += __shfl_xor(acc0, 8);  acc1 += __shfl_xor(acc1, 8);
    acc0 += __shfl_xor(acc0, 16); acc1 += __shfl_xor(acc1, 16);
    acc0 += __shfl_xor(acc0, 32); acc1 += __shfl_xor(acc1, 32);
    if (lane < 8) ((float2*)g)[wid * 8 + lane] = make_float2(acc0, acc1);
}

// ---------------- APPNP step; last step writes d_out directly ----------------
__global__ __launch_bounds__(256) void k_appnp(const int* __restrict__ rowp,
                                               const ushort_t* __restrict__ col,
                                               const float* __restrict__ dinv,
                                               const unsigned int* __restrict__ hs,
                                               const unsigned int* __restrict__ h0p,
                                               unsigned int* __restrict__ hs_out,
                                               const float* __restrict__ Jf,
                                               const int* __restrict__ flag,
                                               void* __restrict__ out, int writeOut) {
    int wid = (blockIdx.x * 256 + threadIdx.x) >> 6;
    int lane = threadIdx.x & 63;
    if (wid >= NN) return;
    int p0 = rowp[wid], p1 = rowp[wid + 1];
    float di = dinv[wid];
    unsigned int hw = h0p[(size_t)wid * 64 + lane];
    float a0 = 0.f, a1 = 0.f;
    int p = p0;
    while (p < p1) {
        int cnt = p1 - p;
        if (cnt > 64) cnt = 64;
        int pl = p + lane;
        int jv = (int)col[pl < p1 ? pl : (p1 - 1)];
        int i = 0;
        for (; i + 8 <= cnt; i += 8) {
            int j0 = __shfl(jv, i),     j1 = __shfl(jv, i + 1);
            int j2 = __shfl(jv, i + 2), j3 = __shfl(jv, i + 3);
            int j4 = __shfl(jv, i + 4), j5 = __shfl(jv, i + 5);
            int j6 = __shfl(jv, i + 6), j7 = __shfl(jv, i + 7);
            unsigned int w0 = hs[j0 * 64 + lane], w1 = hs[j1 * 64 + lane];
            unsigned int w2 = hs[j2 * 64 + lane], w3 = hs[j3 * 64 + lane];
            unsigned int w4 = hs[j4 * 64 + lane], w5 = hs[j5 * 64 + lane];
            unsigned int w6 = hs[j6 * 64 + lane], w7 = hs[j7 * 64 + lane];
            a0 += lo16(w0) + lo16(w1) + lo16(w2) + lo16(w3) +
                  lo16(w4) + lo16(w5) + lo16(w6) + lo16(w7);
            a1 += hi16(w0) + hi16(w1) + hi16(w2) + hi16(w3) +
                  hi16(w4) + hi16(w5) + hi16(w6) + hi16(w7);
        }
        for (; i < cnt; ++i) {
            int j = __shfl(jv, i);
            unsigned int w = hs[j * 64 + lane];
            a0 += lo16(w);
            a1 += hi16(w);
        }
        p += cnt;
    }
    float n0 = 0.9f * di * a0 + 0.1f * lo16(hw);
    float n1 = 0.9f * di * a1 + 0.1f * hi16(hw);
    if (!writeOut) {
        hs_out[(size_t)wid * 64 + lane] = pack2(di * n0, di * n1);
    } else {
        size_t base = (size_t)wid * 129;
        if (*flag) {
            float* o = (float*)out;
            o[base + 2 * lane] = n0;
            o[base + 2 * lane + 1] = n1;
            if (lane == 0) o[base + 128] = Jf[wid];
        } else {
            ushort_t* o = (ushort_t*)out;
            o[base + 2 * lane] = f2bf(n0);
            o[base + 2 * lane + 1] = f2bf(n1);
            if (lane == 0) o[base + 128] = f2bf(Jf[wid]);
        }
    }
}

// ---------------- k_xl: barrier-free direct GEMM, C = A[M,128] @ Bt[128,128]^T ----------
// 32 rows/block, wave w owns cols w*32..w*32+31. All fragments direct global b128 loads.
__global__ __launch_bounds__(256) void k_xl(const ushort_t* __restrict__ A,
                                            const ushort_t* __restrict__ Bt,
                                            ushort_t* __restrict__ outB) {
    int t = threadIdx.x;
    int m0 = blockIdx.x * 32;
    int w = t >> 6, lane = t & 63;
    int row16 = lane & 15, quad = lane >> 4;
    float4_t acc[2][2];
#pragma unroll
    for (int i = 0; i < 2; ++i)
#pragma unroll
        for (int j = 0; j < 2; ++j) acc[i][j] = (float4_t){0.f, 0.f, 0.f, 0.f};
#pragma unroll
    for (int kb = 0; kb < 4; ++kb) {
        int k0 = kb * 32 + quad * 8;
        short8_t afr[2], bfr[2];
        afr[0] = *(const short8_t*)(A + (size_t)(m0 + row16) * 128 + k0);
        afr[1] = *(const short8_t*)(A + (size_t)(m0 + 16 + row16) * 128 + k0);
        bfr[0] = *(const short8_t*)(Bt + (size_t)(w * 32 + row16) * 128 + k0);
        bfr[1] = *(const short8_t*)(Bt + (size_t)(w * 32 + 16 + row16) * 128 + k0);
#pragma unroll
        for (int mt = 0; mt < 2; ++mt)
#pragma unroll
            for (int nt = 0; nt < 2; ++nt)
                acc[mt][nt] = __builtin_amdgcn_mfma_f32_16x16x32_bf16(
                    afr[mt], bfr[nt], acc[mt][nt], 0, 0, 0);
    }
#pragma unroll
    for (int mt = 0; mt < 2; ++mt)
#pragma unroll
        for (int nt = 0; nt < 2; ++nt) {
            int cc = w * 32 + nt * 16 + row16;
#pragma unroll
            for (int r = 0; r < 4; ++r) {
                int rr = m0 + mt * 16 + quad * 4 + r;
                if (rr < NN) outB[(size_t)rr * 128 + cc] = f2bf(acc[mt][nt][r]);
            }
        }
}

// ---------------- k_mlp: fused lin2+lin3 through LDS hidden ----------------
// out = relu(h1@W2+b2)@W3 + b3 + res, + BN stats. 32 rows/block, 1 barrier total.
// Stage1: D1[n][m] = mfma(W2t_frag, h1_frag) -> hid LDS [m][n] (stride HSTR).
// Stage2: D2[m][n2] = mfma(hid_frag, W3t_frag) -> epilogue.
__global__ __launch_bounds__(256) void k_mlp(const ushort_t* __restrict__ h1B,
                                             const ushort_t* __restrict__ w2t,  // [512][128]
                                             const float* __restrict__ b2,
                                             const ushort_t* __restrict__ w3t,  // [128][512]
                                             const float* __restrict__ b3,
                                             const float* __restrict__ res,
                                             float* __restrict__ outF,
                                             float* __restrict__ stats) {
    __shared__ __align__(16) ushort_t hid[32 * HSTR];
    __shared__ float s1[128], s2[128];
    int t = threadIdx.x;
    int m0 = blockIdx.x * 32;
    int w = t >> 6, lane = t & 63;
    int row16 = lane & 15, quad = lane >> 4;
    // ---- stage 1: wave w computes hidden cols [w*128, w*128+128) ----
    float4_t acc1[8][2];
#pragma unroll
    for (int i = 0; i < 8; ++i)
#pragma unroll
        for (int j = 0; j < 2; ++j) acc1[i][j] = (float4_t){0.f, 0.f, 0.f, 0.f};
#pragma unroll
    for (int kb = 0; kb < 4; ++kb) {
        int k0 = kb * 32 + quad * 8;
        short8_t bfr[2];
        bfr[0] = *(const short8_t*)(h1B + (size_t)(m0 + row16) * 128 + k0);
        bfr[1] = *(const short8_t*)(h1B + (size_t)(m0 + 16 + row16) * 128 + k0);
#pragma unroll
        for (int nt = 0; nt < 8; ++nt) {
            short8_t afr = *(const short8_t*)(w2t + (size_t)(w * 128 + nt * 16 + row16) * 128 + k0);
            acc1[nt][0] = __builtin_amdgcn_mfma_f32_16x16x32_bf16(afr, bfr[0], acc1[nt][0], 0, 0, 0);
            acc1[nt][1] = __builtin_amdgcn_mfma_f32_16x16x32_bf16(afr, bfr[1], acc1[nt][1], 0, 0, 0);
        }
    }
    if (t < 128) { s1[t] = 0.f; s2[t] = 0.f; }
    // write hid: lane holds n = base+quad*4+r (rows of D1), m = mt*16+row16 (cols of D1)
#pragma unroll
    for (int nt = 0; nt < 8; ++nt) {
        int nb = w * 128 + nt * 16 + quad * 4;
        float4 bv = *(const float4*)(b2 + nb);
#pragma unroll
        for (int mt = 0; mt < 2; ++mt) {
            int m = mt * 16 + row16;
            float v0 = acc1[nt][mt][0] + bv.x; v0 = v0 > 0.f ? v0 : 0.f;
            float v1 = acc1[nt][mt][1] + bv.y; v1 = v1 > 0.f ? v1 : 0.f;
            float v2 = acc1[nt][mt][2] + bv.z; v2 = v2 > 0.f ? v2 : 0.f;
            float v3 = acc1[nt][mt][3] + bv.w; v3 = v3 > 0.f ? v3 : 0.f;
            *(unsigned int*)(hid + m * HSTR + nb)     = pack2(v0, v1);
            *(unsigned int*)(hid + m * HSTR + nb + 2) = pack2(v2, v3);
        }
    }
    __syncthreads();
    // ---- stage 2: wave w computes out cols [w*32, w*32+32) ----
    float4_t acc2[2][2];
#pragma unroll
    for (int i = 0; i < 2; ++i)
#pragma unroll
        for (int j = 0; j < 2; ++j) acc2[i][j] = (float4_t){0.f, 0.f, 0.f, 0.f};
    for (int kb = 0; kb < 16; ++kb) {
        int k0 = kb * 32 + quad * 8;
        short8_t afr[2], bfr[2];
        afr[0] = *(const short8_t*)(hid + row16 * HSTR + k0);
        afr[1] = *(const short8_t*)(hid + (16 + row16) * HSTR + k0);
        bfr[0] = *(const short8_t*)(w3t + (size_t)(w * 32 + row16) * 512 + k0);
        bfr[1] = *(const short8_t*)(w3t + (size_t)(w * 32 + 16 + row16) * 512 + k0);
#pragma unroll
        for (int mt = 0; mt < 2; ++mt)
#pragma unroll
            for (int nt = 0; nt < 2; ++nt)
                acc2[mt][nt] = __builtin_amdgcn_mfma_f32_16x16x32_bf16(
                    afr[mt], bfr[nt], acc2[mt][nt], 0, 0, 0);
    }
    // epilogue: out = acc2 + b3 + res, BN stats
#pragma unroll
    for (int mt = 0; mt < 2; ++mt) {
#pragma unroll
        for (int nt = 0; nt < 2; ++nt) {
            int cc = w * 32 + nt * 16 + row16;
            float bv = b3[cc];
            float ls = 0.f, lq = 0.f;
#pragma unroll
            for (int r = 0; r < 4; ++r) {
                int rr = m0 + mt * 16 + quad * 4 + r;
                if (rr < NN) {
                    float v = acc2[mt][nt][r] + bv + res[(size_t)rr * 128 + cc];
                    outF[(size_t)rr * 128 + cc] = v;
                    ls += v;
                    lq += v * v;
                }
            }
            atomicAdd(&s1[cc], ls);
            atomicAdd(&s2[cc], lq);
        }
    }
    __syncthreads();
    if (t < 128) {
        atomicAdd(&stats[t], s1[t]);
        atomicAdd(&stats[128 + t], s2[t]);
    }
}

// ---------------- host ----------------
extern "C" void kernel_launch(void* const* d_in, const int* in_sizes, int n_in,
                              void* d_out, int out_size, void* d_ws, size_t ws_size,
                              hipStream_t stream) {
    const int* ei = (const int*)d_in[2];

    char* p = (char*)d_ws;
    auto alloc = [&](size_t bytes) {
        void* r = (void*)p;
        p += (bytes + 255) & ~(size_t)255;
        return r;
    };
    float*    Af    = (float*)alloc((size_t)NN * DEMB * 4);   // h f32
    float*    Cf    = (float*)alloc((size_t)NN * DEMB * 4);   // h1 f32
    ushort_t* hB    = (ushort_t*)alloc((size_t)NP * DEMB * 2);   // padded
    ushort_t* h1B   = (ushort_t*)alloc((size_t)NP * DEMB * 2);   // padded
    ushort_t* xlB   = (ushort_t*)alloc((size_t)NN * DEMB * 2);
    unsigned int* hsA  = (unsigned int*)alloc((size_t)NN * 64 * 4);
    unsigned int* hsB_ = (unsigned int*)alloc((size_t)NN * 64 * 4);
    unsigned int* h0p  = (unsigned int*)alloc((size_t)NN * 64 * 4);
    float*    asv   = (float*)alloc((size_t)NN * 8 * 4);
    float*    adv   = (float*)alloc((size_t)NN * 8 * 4);
    float*    gv    = (float*)alloc((size_t)NN * 16 * 4);
    float*    dinvv = (float*)alloc((size_t)NN * 4);
    float*    stats = (float*)alloc(4 * 256 * 4);
    int*      deg   = (int*)alloc((size_t)NN * 4);
    int*      rowp  = (int*)alloc((size_t)(NN + 1) * 4);
    int*      fill  = (int*)alloc((size_t)NN * 4);
    ushort_t* colv  = (ushort_t*)alloc((size_t)EP * 2);
    int*      part  = (int*)alloc(NB_SCAN * 4);
    int*      poff  = (int*)alloc(NB_SCAN * 4);
    int*      flag  = (int*)alloc(256);
    ushort_t* wtg   = (ushort_t*)alloc((size_t)2 * 128 * 128 * 2);
    ushort_t* wt2   = (ushort_t*)alloc((size_t)2 * 512 * 128 * 2);
    ushort_t* wt3   = (ushort_t*)alloc((size_t)2 * 128 * 512 * 2);
    float* xf   = (float*)alloc((size_t)NN * 2 * 4);
    float* Jf   = (float*)alloc((size_t)NN * 4);
    float* l0wF = (float*)alloc(384 * 4);
    float* l0bF = (float*)alloc(128 * 4);
    float* gwF  = (float*)alloc(32768 * 4);
    float* asF  = (float*)alloc(256 * 4);
    float* adF  = (float*)alloc(256 * 4);
    float* w1F  = (float*)alloc(4096 * 4);
    float* b1gF = (float*)alloc(256 * 4);
    float* b1bF = (float*)alloc(256 * 4);
    float* w2F  = (float*)alloc(131072 * 4);
    float* b2F  = (float*)alloc(1024 * 4);
    float* w3F  = (float*)alloc(131072 * 4);
    float* b3F  = (float*)alloc(256 * 4);
    float* b2gF = (float*)alloc(256 * 4);
    float* b2bF = (float*)alloc(256 * 4);

    // ---- dtype detect + batched canonicalize ----
    k_detect<<<1, 64, 0, stream>>>((const unsigned int*)d_in[1], flag);
    CvtArgs ca;
    {
        const int srcIdx[16] = {0, 1, 3, 4, 5, 6, 7, 8, 9, 10, 11, 12, 13, 14, 15, 16};
        float* dsts[16] = {xf, Jf, l0wF, l0bF, gwF, asF, adF, w1F, b1gF, b1bF,
                           w2F, b2F, w3F, b3F, b2gF, b2bF};
        const int ns[16] = {NN * 2, NN, 384, 128, 32768, 256, 256, 4096, 256, 256,
                            131072, 1024, 131072, 256, 256, 256};
        for (int i = 0; i < 16; ++i) { ca.src[i] = d_in[srcIdx[i]]; ca.dst[i] = dsts[i]; ca.n[i] = ns[i]; }
    }
    k_cvt_all<<<dim3(cdiv(131072, 256), 16), 256, 0, stream>>>(ca, flag);

    // ---- CSR build ----
    hipMemsetAsync(deg, 0, (size_t)NN * 4, stream);
    hipMemsetAsync(stats, 0, 4 * 256 * 4, stream);
    k_deg<<<cdiv(EP, 256), 256, 0, stream>>>(ei, deg);
    k_part<<<NB_SCAN, 256, 0, stream>>>(deg, part);
    k_scan2<<<1, 256, 0, stream>>>(part, poff, rowp);
    k_rowp<<<NB_SCAN, 256, 0, stream>>>(deg, poff, rowp, dinvv, fill);
    k_fill<<<cdiv(EP, 256), 256, 0, stream>>>(ei, fill, colv);

    // ---- batched weight transposes ----
    TrArgs ta;
    {
        const float* srcs[6] = {gwF, gwF + 16384, w2F, w2F + 65536, w3F, w3F + 65536};
        ushort_t* dsts[6] = {wtg, wtg + 16384, wt2, wt2 + 65536, wt3, wt3 + 65536};
        const int Ks[6] = {128, 128, 128, 128, 512, 512};
        const int Ncs[6] = {128, 128, 512, 512, 128, 128};
        for (int i = 0; i < 6; ++i) { ta.src[i] = srcs[i]; ta.dst[i] = dsts[i]; ta.K[i] = Ks[i]; ta.Nc[i] = Ncs[i]; }
    }
    k_tr_all<<<dim3(cdiv(65536, 256), 6), 256, 0, stream>>>(ta);

    // ---- input projection ----
    k_lin0<<<cdiv(NN * DEMB, 256), 256, 0, stream>>>(xf, Jf, l0wF, l0bF, Af, hB);

    for (int l = 0; l < 2; ++l) {
        float* st1 = stats + (l * 2 + 0) * 256;
        float* st2 = stats + (l * 2 + 1) * 256;
        // xl (bf16) = h @ gat_w[l]   (direct, barrier-free, grid 1563)
        k_xl<<<NMT32, 256, 0, stream>>>(hB, wtg + l * 16384, xlB);
        k_att<<<cdiv(NN * 8, 256), 256, 0, stream>>>((const unsigned int*)xlB, asF + l * 128,
                                                     adF + l * 128, asv, adv);
        k_gat<<<cdiv(NN * 64, 256), 256, 0, stream>>>(rowp, colv, asv, adv,
                                                      (const unsigned int*)xlB, gv);
        k_z1s<<<512, 256, 0, stream>>>(Af, gv, w1F + l * 2048, st1);
        k_bnapply1<<<cdiv(NN * DEMB, 256), 256, 0, stream>>>(Af, gv, w1F + l * 2048, st1,
                                                             b1gF + l * 128, b1bF + l * 128,
                                                             Cf, h1B);
        // fused MLP: Af = relu(h1@W2+b2)@W3 + b3 + Cf, + BN2 stats
        k_mlp<<<NMT32, 256, 0, stream>>>(h1B, wt2 + l * 65536, b2F + l * 512,
                                         wt3 + l * 65536, b3F + l * 128,
                                         Cf, Af, st2);
        if (l == 0) {
            k_bnapply<<<cdiv(NN * DEMB, 256), 256, 0, stream>>>(Af, st2, b2gF, b2bF, Af, hB);
        } else {
            k_bnapply_fin<<<cdiv(NN * 64, 256), 256, 0, stream>>>(Af, st2, b2gF + 128, b2bF + 128,
                                                                  dinvv, hsA, h0p);
        }
    }

    // ---- APPNP: 10 steps; last writes d_out ----
    unsigned int* pin = hsA;
    unsigned int* pout = hsB_;
    for (int k = 0; k < 10; ++k) {
        int last = (k == 9) ? 1 : 0;
        k_appnp<<<cdiv(NN * 64, 256), 256, 0, stream>>>(rowp, colv, dinvv, pin, h0p, pout,
                                                        Jf, flag, d_out, last);
        unsigned int* tmp = pout;
        pout = pin;
        pin = tmp;
    }
}

// Round 10
// 936.293 us; speedup vs baseline: 1.0555x; 1.0555x over previous
//
#include <hip/hip_runtime.h>

#define NN 50000
#define NP 50048   // padded rows for global_load_lds tail reads
#define NMT64 782  // cdiv(NN,64)
#define NE 800000
#define EP (NE + NN)
#define DEMB 128
#define DHID 512
#define NB_SCAN 196  // cdiv(NN,256)

typedef unsigned short ushort_t;
typedef __attribute__((ext_vector_type(8))) short short8_t;
typedef __attribute__((ext_vector_type(4))) float float4_t;

__device__ __forceinline__ float bf2f(ushort_t u) {
    return __uint_as_float(((unsigned int)u) << 16);
}
__device__ __forceinline__ ushort_t f2bf(float f) {
    unsigned int x = __float_as_uint(f);
    x += 0x7fffu + ((x >> 16) & 1u);
    return (ushort_t)(x >> 16);
}
__device__ __forceinline__ float lo16(unsigned int w) { return __uint_as_float(w << 16); }
__device__ __forceinline__ float hi16(unsigned int w) { return __uint_as_float(w & 0xffff0000u); }
__device__ __forceinline__ unsigned int pack2(float a, float b) {
    return (unsigned int)f2bf(a) | ((unsigned int)f2bf(b) << 16);
}
__device__ __forceinline__ void gl_lds16(const ushort_t* g, ushort_t* l) {
    __builtin_amdgcn_global_load_lds(
        (const __attribute__((address_space(1))) void*)g,
        (__attribute__((address_space(3))) void*)l, 16, 0, 0);
}
static inline int cdiv(int a, int b) { return (a + b - 1) / b; }

// ---------------- dtype detect + batched convert ----------------
__global__ void k_detect(const unsigned int* __restrict__ Jw, int* __restrict__ flag) {
    if (threadIdx.x != 0 || blockIdx.x != 0) return;
    int votes = 0;
    for (int i = 0; i < 8; ++i) {
        unsigned int w = Jw[i];
        unsigned int ex = (w >> 23) & 0xFFu;
        if ((w >> 31) == 0u && ex >= 100u && ex <= 126u) votes++;
    }
    *flag = (votes >= 6) ? 1 : 0;
}

struct CvtArgs {
    const void* src[16];
    float* dst[16];
    int n[16];
};
__global__ void k_cvt_all(CvtArgs a, const int* __restrict__ flag) {
    int which = blockIdx.y;
    int i = blockIdx.x * 256 + threadIdx.x;
    if (i >= a.n[which]) return;
    float v;
    if (*flag) v = ((const float*)a.src[which])[i];
    else       v = bf2f(((const ushort_t*)a.src[which])[i]);
    a.dst[which][i] = v;
}

struct TrArgs {
    const float* src[6];
    ushort_t* dst[6];
    int K[6];
    int Nc[6];
};
__global__ void k_tr_all(TrArgs a) {
    int which = blockIdx.y;
    int idx = blockIdx.x * 256 + threadIdx.x;
    int K = a.K[which], Nc = a.Nc[which];
    if (idx >= K * Nc) return;
    int k = idx / Nc, n = idx - k * Nc;
    a.dst[which][n * K + k] = f2bf(a.src[which][idx]);
}

// ---------------- CSR build ----------------
__global__ void k_deg(const int* __restrict__ ei, int* __restrict__ deg) {
    int e = blockIdx.x * 256 + threadIdx.x;
    if (e >= EP) return;
    int d = (e < NE) ? ei[NE + e] : (e - NE);
    atomicAdd(&deg[d], 1);
}

__global__ void k_part(const int* __restrict__ deg, int* __restrict__ part) {
    __shared__ int sm[256];
    int i = blockIdx.x * 256 + threadIdx.x;
    int v = (i < NN) ? deg[i] : 0;
    sm[threadIdx.x] = v;
    __syncthreads();
    for (int off = 128; off > 0; off >>= 1) {
        if (threadIdx.x < off) sm[threadIdx.x] += sm[threadIdx.x + off];
        __syncthreads();
    }
    if (threadIdx.x == 0) part[blockIdx.x] = sm[0];
}

__global__ void k_scan2(const int* __restrict__ part, int* __restrict__ poff,
                        int* __restrict__ rowp) {
    __shared__ int sm[256];
    int t = threadIdx.x;
    int v = (t < NB_SCAN) ? part[t] : 0;
    sm[t] = v;
    __syncthreads();
    int incl = v;
    for (int off = 1; off < 256; off <<= 1) {
        int u = (t >= off) ? sm[t - off] : 0;
        __syncthreads();
        incl += u;
        sm[t] = incl;
        __syncthreads();
    }
    if (t < NB_SCAN) poff[t] = incl - v;
    if (t == 255) rowp[NN] = sm[255];
}

// rowp + dinv + fill-init fused
__global__ void k_rowp(const int* __restrict__ deg, const int* __restrict__ poff,
                       int* __restrict__ rowp, float* __restrict__ dinv,
                       int* __restrict__ fill) {
    __shared__ int sm[256];
    int i = blockIdx.x * 256 + threadIdx.x;
    int t = threadIdx.x;
    int v = (i < NN) ? deg[i] : 0;
    sm[t] = v;
    __syncthreads();
    int incl = v;
    for (int off = 1; off < 256; off <<= 1) {
        int u = (t >= off) ? sm[t - off] : 0;
        __syncthreads();
        incl += u;
        sm[t] = incl;
        __syncthreads();
    }
    if (i < NN) {
        int rp = poff[blockIdx.x] + incl - v;
        rowp[i] = rp;
        fill[i] = rp;
        dinv[i] = rsqrtf(fmaxf((float)v, 1.0f));
    }
}

__global__ void k_fill(const int* __restrict__ ei, int* __restrict__ fillpos,
                       ushort_t* __restrict__ col) {
    int e = blockIdx.x * 256 + threadIdx.x;
    if (e >= EP) return;
    int s, d;
    if (e < NE) { s = ei[e]; d = ei[NE + e]; } else { s = d = e - NE; }
    int pos = atomicAdd(&fillpos[d], 1);
    col[pos] = (ushort_t)s;
}

// ---------------- elementwise ----------------
__global__ void k_lin0(const float* __restrict__ x, const float* __restrict__ J,
                       const float* __restrict__ w, const float* __restrict__ b,
                       ushort_t* __restrict__ hB) {
    int idx = blockIdx.x * 256 + threadIdx.x;
    if (idx >= NN * DEMB) return;
    int n = idx >> 7, d = idx & 127;
    float v = x[n * 2] * w[d] + x[n * 2 + 1] * w[DEMB + d] + J[n] * w[2 * DEMB + d] + b[d];
    hB[idx] = f2bf(v);
}

__global__ void k_att(const unsigned int* __restrict__ xlB, const float* __restrict__ asrc,
                      const float* __restrict__ adst, float* __restrict__ a_s,
                      float* __restrict__ a_d) {
    int idx = blockIdx.x * 256 + threadIdx.x;
    if (idx >= NN * 8) return;
    int n = idx >> 3, hh = idx & 7;
    const unsigned int* row = xlB + (size_t)n * 64 + hh * 8;
    float s = 0.f, d = 0.f;
#pragma unroll
    for (int c = 0; c < 8; ++c) {
        unsigned int w = row[c];
        float v0 = lo16(w), v1 = hi16(w);
        s += v0 * asrc[hh * 16 + 2 * c] + v1 * asrc[hh * 16 + 2 * c + 1];
        d += v0 * adst[hh * 16 + 2 * c] + v1 * adst[hh * 16 + 2 * c + 1];
    }
    a_s[idx] = s;
    a_d[idx] = d;
}

// BN1 stats pass: recompute z = h + g@w1 (h from bf16), accumulate stats only
__global__ __launch_bounds__(256) void k_z1s(const ushort_t* __restrict__ hB,
                                             const float* __restrict__ g,
                                             const float* __restrict__ w1,
                                             float* __restrict__ stats) {
    int d = threadIdx.x & 127;
    int rstart = blockIdx.x * 2 + (threadIdx.x >> 7);
    int stride = gridDim.x * 2;
    float s1 = 0.f, s2 = 0.f;
    for (int r = rstart; r < NN; r += stride) {
        const float* gr = g + r * 16;
        float s = bf2f(hB[(size_t)r * DEMB + d]);
#pragma unroll
        for (int c = 0; c < 16; ++c) s += gr[c] * w1[c * DEMB + d];
        s1 += s;
        s2 += s * s;
    }
    __shared__ float b1[256], b2[256];
    b1[threadIdx.x] = s1;
    b2[threadIdx.x] = s2;
    __syncthreads();
    if (threadIdx.x < 128) {
        atomicAdd(&stats[threadIdx.x], b1[threadIdx.x] + b1[threadIdx.x + 128]);
        atomicAdd(&stats[128 + threadIdx.x], b2[threadIdx.x] + b2[threadIdx.x + 128]);
    }
}

// BN1 apply with recompute (h from bf16); out h1 bf16 only
__global__ void k_bnapply1(const ushort_t* __restrict__ hB, const float* __restrict__ g,
                           const float* __restrict__ w1, const float* __restrict__ stats,
                           const float* __restrict__ gam, const float* __restrict__ bet,
                           ushort_t* __restrict__ outB) {
    int idx = blockIdx.x * 256 + threadIdx.x;
    if (idx >= NN * DEMB) return;
    int n = idx >> 7, d = idx & 127;
    float s = bf2f(hB[idx]);
    const float* gr = g + n * 16;
#pragma unroll
    for (int c = 0; c < 16; ++c) s += gr[c] * w1[c * DEMB + d];
    const float invN = 1.0f / (float)NN;
    float mu = stats[d] * invN;
    float var = stats[128 + d] * invN - mu * mu;
    float rs = rsqrtf(fmaxf(var, 0.f) + 1e-5f);
    float v = gam[d] * (s - mu) * rs + bet[d];
    outB[idx] = f2bf(v);
}

// BN2 apply (layer 0): z from bf16; out hB bf16
__global__ void k_bnapply(const ushort_t* __restrict__ zB, const float* __restrict__ stats,
                          const float* __restrict__ gam, const float* __restrict__ bet,
                          ushort_t* __restrict__ outB) {
    int idx = blockIdx.x * 256 + threadIdx.x;
    if (idx >= NN * DEMB) return;
    int d = idx & 127;
    const float invN = 1.0f / (float)NN;
    float mu = stats[d] * invN;
    float var = stats[128 + d] * invN - mu * mu;
    float rs = rsqrtf(fmaxf(var, 0.f) + 1e-5f);
    float v = gam[d] * (bf2f(zB[idx]) - mu) * rs + bet[d];
    outB[idx] = f2bf(v);
}

// BN2 apply (layer 1, final): z from bf16; emit APPNP inputs directly
__global__ void k_bnapply_fin(const unsigned int* __restrict__ zB, const float* __restrict__ stats,
                              const float* __restrict__ gam, const float* __restrict__ bet,
                              const float* __restrict__ dinv,
                              unsigned int* __restrict__ hs, unsigned int* __restrict__ h0p) {
    int idx = blockIdx.x * 256 + threadIdx.x;
    if (idx >= NN * 64) return;
    int n = idx >> 6, d0 = (idx & 63) * 2;
    const float invN = 1.0f / (float)NN;
    unsigned int zw = zB[idx];
    float z0 = lo16(zw), z1 = hi16(zw);
    float mu0 = stats[d0] * invN, mu1 = stats[d0 + 1] * invN;
    float v0 = stats[128 + d0] * invN - mu0 * mu0;
    float v1 = stats[128 + d0 + 1] * invN - mu1 * mu1;
    float rs0 = rsqrtf(fmaxf(v0, 0.f) + 1e-5f);
    float rs1 = rsqrtf(fmaxf(v1, 0.f) + 1e-5f);
    float a = gam[d0] * (z0 - mu0) * rs0 + bet[d0];
    float b = gam[d0 + 1] * (z1 - mu1) * rs1 + bet[d0 + 1];
    float di = dinv[n];
    hs[idx] = pack2(di * a, di * b);
    h0p[idx] = pack2(a, b);
}

// ---------------- GAT: single-pass softmax-aggregate (wave per node) ----------------
__global__ __launch_bounds__(256) void k_gat(const int* __restrict__ rowp,
                                             const ushort_t* __restrict__ col,
                                             const float* __restrict__ a_s, const float* __restrict__ a_d,
                                             const unsigned int* __restrict__ xlB, float* __restrict__ g) {
    int wid = (blockIdx.x * 256 + threadIdx.x) >> 6;
    int lane = threadIdx.x & 63;
    if (wid >= NN) return;
    int p0 = rowp[wid], p1 = rowp[wid + 1];
    int hh = lane >> 3;
    float ad2 = a_d[wid * 8 + hh];
    float acc0 = 0.f, acc1 = 0.f, s = 0.f;
    int p = p0;
    while (p < p1) {
        int cnt = p1 - p;
        if (cnt > 64) cnt = 64;
        int pl = p + lane;
        int jv = (int)col[pl < p1 ? pl : (p1 - 1)];
        int i = 0;
        for (; i + 8 <= cnt; i += 8) {
            int j0 = __shfl(jv, i),     j1 = __shfl(jv, i + 1);
            int j2 = __shfl(jv, i + 2), j3 = __shfl(jv, i + 3);
            int j4 = __shfl(jv, i + 4), j5 = __shfl(jv, i + 5);
            int j6 = __shfl(jv, i + 6), j7 = __shfl(jv, i + 7);
            float e0 = a_s[j0 * 8 + hh] + ad2, e1 = a_s[j1 * 8 + hh] + ad2;
            float e2 = a_s[j2 * 8 + hh] + ad2, e3 = a_s[j3 * 8 + hh] + ad2;
            float e4 = a_s[j4 * 8 + hh] + ad2, e5 = a_s[j5 * 8 + hh] + ad2;
            float e6 = a_s[j6 * 8 + hh] + ad2, e7 = a_s[j7 * 8 + hh] + ad2;
            unsigned int w0 = xlB[j0 * 64 + lane], w1 = xlB[j1 * 64 + lane];
            unsigned int w2 = xlB[j2 * 64 + lane], w3 = xlB[j3 * 64 + lane];
            unsigned int w4 = xlB[j4 * 64 + lane], w5 = xlB[j5 * 64 + lane];
            unsigned int w6 = xlB[j6 * 64 + lane], w7 = xlB[j7 * 64 + lane];
            e0 = e0 > 0.f ? e0 : 0.2f * e0;  e1 = e1 > 0.f ? e1 : 0.2f * e1;
            e2 = e2 > 0.f ? e2 : 0.2f * e2;  e3 = e3 > 0.f ? e3 : 0.2f * e3;
            e4 = e4 > 0.f ? e4 : 0.2f * e4;  e5 = e5 > 0.f ? e5 : 0.2f * e5;
            e6 = e6 > 0.f ? e6 : 0.2f * e6;  e7 = e7 > 0.f ? e7 : 0.2f * e7;
            float al0 = __expf(e0), al1 = __expf(e1), al2 = __expf(e2), al3 = __expf(e3);
            float al4 = __expf(e4), al5 = __expf(e5), al6 = __expf(e6), al7 = __expf(e7);
            s += al0 + al1 + al2 + al3 + al4 + al5 + al6 + al7;
            acc0 += al0 * lo16(w0) + al1 * lo16(w1) + al2 * lo16(w2) + al3 * lo16(w3) +
                    al4 * lo16(w4) + al5 * lo16(w5) + al6 * lo16(w6) + al7 * lo16(w7);
            acc1 += al0 * hi16(w0) + al1 * hi16(w1) + al2 * hi16(w2) + al3 * hi16(w3) +
                    al4 * hi16(w4) + al5 * hi16(w5) + al6 * hi16(w6) + al7 * hi16(w7);
        }
        for (; i < cnt; ++i) {
            int j = __shfl(jv, i);
            float e = a_s[j * 8 + hh] + ad2;
            e = e > 0.f ? e : 0.2f * e;
            float al = __expf(e);
            unsigned int w = xlB[j * 64 + lane];
            s += al;
            acc0 += al * lo16(w);
            acc1 += al * hi16(w);
        }
        p += cnt;
    }
    float inv = 1.f / s;
    acc0 *= inv;
    acc1 *= inv;
    acc0 += __shfl_xor(acc0, 8);  acc1 += __shfl_xor(acc1, 8);
    acc0 += __shfl_xor(acc0, 16); acc1 += __shfl_xor(acc1, 16);
    acc0 += __shfl_xor(acc0, 32); acc1 += __shfl_xor(acc1, 32);
    if (lane < 8) ((float2*)g)[wid * 8 + lane] = make_float2(acc0, acc1);
}

// ---------------- APPNP step; last step writes d_out directly ----------------
__global__ __launch_bounds__(256) void k_appnp(const int* __restrict__ rowp,
                                               const ushort_t* __restrict__ col,
                                               const float* __restrict__ dinv,
                                               const unsigned int* __restrict__ hs,
                                               const unsigned int* __restrict__ h0p,
                                               unsigned int* __restrict__ hs_out,
                                               const float* __restrict__ Jf,
                                               const int* __restrict__ flag,
                                               void* __restrict__ out, int writeOut) {
    int wid = (blockIdx.x * 256 + threadIdx.x) >> 6;
    int lane = threadIdx.x & 63;
    if (wid >= NN) return;
    int p0 = rowp[wid], p1 = rowp[wid + 1];
    float di = dinv[wid];
    unsigned int hw = h0p[(size_t)wid * 64 + lane];
    float a0 = 0.f, a1 = 0.f;
    int p = p0;
    while (p < p1) {
        int cnt = p1 - p;
        if (cnt > 64) cnt = 64;
        int pl = p + lane;
        int jv = (int)col[pl < p1 ? pl : (p1 - 1)];
        int i = 0;
        for (; i + 8 <= cnt; i += 8) {
            int j0 = __shfl(jv, i),     j1 = __shfl(jv, i + 1);
            int j2 = __shfl(jv, i + 2), j3 = __shfl(jv, i + 3);
            int j4 = __shfl(jv, i + 4), j5 = __shfl(jv, i + 5);
            int j6 = __shfl(jv, i + 6), j7 = __shfl(jv, i + 7);
            unsigned int w0 = hs[j0 * 64 + lane], w1 = hs[j1 * 64 + lane];
            unsigned int w2 = hs[j2 * 64 + lane], w3 = hs[j3 * 64 + lane];
            unsigned int w4 = hs[j4 * 64 + lane], w5 = hs[j5 * 64 + lane];
            unsigned int w6 = hs[j6 * 64 + lane], w7 = hs[j7 * 64 + lane];
            a0 += lo16(w0) + lo16(w1) + lo16(w2) + lo16(w3) +
                  lo16(w4) + lo16(w5) + lo16(w6) + lo16(w7);
            a1 += hi16(w0) + hi16(w1) + hi16(w2) + hi16(w3) +
                  hi16(w4) + hi16(w5) + hi16(w6) + hi16(w7);
        }
        for (; i < cnt; ++i) {
            int j = __shfl(jv, i);
            unsigned int w = hs[j * 64 + lane];
            a0 += lo16(w);
            a1 += hi16(w);
        }
        p += cnt;
    }
    float n0 = 0.9f * di * a0 + 0.1f * lo16(hw);
    float n1 = 0.9f * di * a1 + 0.1f * hi16(hw);
    if (!writeOut) {
        hs_out[(size_t)wid * 64 + lane] = pack2(di * n0, di * n1);
    } else {
        size_t base = (size_t)wid * 129;
        if (*flag) {
            float* o = (float*)out;
            o[base + 2 * lane] = n0;
            o[base + 2 * lane + 1] = n1;
            if (lane == 0) o[base + 128] = Jf[wid];
        } else {
            ushort_t* o = (ushort_t*)out;
            o[base + 2 * lane] = f2bf(n0);
            o[base + 2 * lane + 1] = f2bf(n1);
            if (lane == 0) o[base + 128] = f2bf(Jf[wid]);
        }
    }
}

// ---------------- 64x128-tile MFMA GEMM, double-buffered ----------
// MODE 1: outB = bf16(relu(acc+bias)); MODE 2: outB = bf16(acc+bias+bf2f(res)) +BN stats;
// MODE 3: outB = bf16(acc)
template <int MODE>
__global__ __launch_bounds__(256) void k_gemm64(const ushort_t* __restrict__ A,
                                                const ushort_t* __restrict__ Bt,
                                                int M, int K, int Nc,
                                                const float* __restrict__ bias,
                                                const ushort_t* __restrict__ res,
                                                ushort_t* __restrict__ outB,
                                                float* __restrict__ stats) {
    __shared__ __align__(16) ushort_t lsA[2][64 * 32];
    __shared__ __align__(16) ushort_t lsB[2][128 * 32];
    int t = threadIdx.x;
    int m0 = blockIdx.x * 64;
    int n0 = blockIdx.y * 128;
    int w = t >> 6, lane = t & 63;
    int row16 = lane & 15, quad = lane >> 4;
    int nbase = w * 32;
    float4_t acc[8];
#pragma unroll
    for (int i = 0; i < 8; ++i) acc[i] = (float4_t){0.f, 0.f, 0.f, 0.f};
    int lrow = lane >> 2;
    int lcol = (lane & 3) * 8;
    const ushort_t* gA  = A  + (size_t)(m0 + w * 16 + lrow) * K + lcol;
    const ushort_t* gB0 = Bt + (size_t)(n0 + w * 32 + lrow) * K + lcol;
    const ushort_t* gB1 = Bt + (size_t)(n0 + w * 32 + 16 + lrow) * K + lcol;
    ushort_t* dA  = &lsA[0][0] + (w * 16) * 32;
    ushort_t* dB0 = &lsB[0][0] + (w * 32) * 32;
    ushort_t* dB1 = &lsB[0][0] + (w * 32 + 16) * 32;
    const int bufStrideA = 64 * 32, bufStrideB = 128 * 32;
    const int nK = K >> 5;
    gl_lds16(gA, dA);
    gl_lds16(gB0, dB0);
    gl_lds16(gB1, dB1);
    for (int kb = 0; kb < nK; ++kb) {
        __syncthreads();
        int nb = kb + 1;
        if (nb < nK) {
            int b = nb & 1;
            int k0 = nb << 5;
            gl_lds16(gA + k0, dA + b * bufStrideA);
            gl_lds16(gB0 + k0, dB0 + b * bufStrideB);
            gl_lds16(gB1 + k0, dB1 + b * bufStrideB);
        }
        const ushort_t* la = &lsA[kb & 1][0];
        const ushort_t* lb = &lsB[kb & 1][0];
        short8_t afr[4], bfr[2];
#pragma unroll
        for (int i = 0; i < 4; ++i)
            afr[i] = *(const short8_t*)(la + (i * 16 + row16) * 32 + quad * 8);
#pragma unroll
        for (int i = 0; i < 2; ++i)
            bfr[i] = *(const short8_t*)(lb + (nbase + i * 16 + row16) * 32 + quad * 8);
#pragma unroll
        for (int mt = 0; mt < 4; ++mt)
#pragma unroll
            for (int nt = 0; nt < 2; ++nt)
                acc[mt * 2 + nt] = __builtin_amdgcn_mfma_f32_16x16x32_bf16(
                    afr[mt], bfr[nt], acc[mt * 2 + nt], 0, 0, 0);
    }
    if (MODE == 2) {
        __shared__ float s1[128], s2[128];
        if (t < 128) { s1[t] = 0.f; s2[t] = 0.f; }
        __syncthreads();
#pragma unroll
        for (int mt = 0; mt < 4; ++mt) {
#pragma unroll
            for (int nt = 0; nt < 2; ++nt) {
                int cb = nbase + nt * 16 + row16;
                int cc = n0 + cb;
                float bv = bias[cc];
                float ls = 0.f, lq = 0.f;
#pragma unroll
                for (int r = 0; r < 4; ++r) {
                    int rr = m0 + mt * 16 + quad * 4 + r;
                    if (rr < M) {
                        float v = acc[mt * 2 + nt][r] + bv + bf2f(res[(size_t)rr * Nc + cc]);
                        outB[(size_t)rr * Nc + cc] = f2bf(v);
                        ls += v;
                        lq += v * v;
                    }
                }
                atomicAdd(&s1[cb], ls);
                atomicAdd(&s2[cb], lq);
            }
        }
        __syncthreads();
        if (t < 128) {
            atomicAdd(&stats[n0 + t], s1[t]);
            atomicAdd(&stats[128 + n0 + t], s2[t]);
        }
    } else {
#pragma unroll
        for (int mt = 0; mt < 4; ++mt) {
#pragma unroll
            for (int nt = 0; nt < 2; ++nt) {
                int cc = n0 + nbase + nt * 16 + row16;
                float bv = (MODE == 1) ? bias[cc] : 0.f;
#pragma unroll
                for (int r = 0; r < 4; ++r) {
                    int rr = m0 + mt * 16 + quad * 4 + r;
                    if (rr < M) {
                        float v = acc[mt * 2 + nt][r];
                        if (MODE == 1) {
                            v += bv;
                            v = v > 0.f ? v : 0.f;
                        }
                        outB[(size_t)rr * Nc + cc] = f2bf(v);
                    }
                }
            }
        }
    }
}

// ---------------- host ----------------
extern "C" void kernel_launch(void* const* d_in, const int* in_sizes, int n_in,
                              void* d_out, int out_size, void* d_ws, size_t ws_size,
                              hipStream_t stream) {
    const int* ei = (const int*)d_in[2];

    char* p = (char*)d_ws;
    auto alloc = [&](size_t bytes) {
        void* r = (void*)p;
        p += (bytes + 255) & ~(size_t)255;
        return r;
    };
    ushort_t* hB    = (ushort_t*)alloc((size_t)NP * DEMB * 2);   // h (padded)
    ushort_t* h1B   = (ushort_t*)alloc((size_t)NP * DEMB * 2);   // h1 (padded)
    ushort_t* xlB   = (ushort_t*)alloc((size_t)NN * DEMB * 2);   // xl, reused as zB
    unsigned int* hsA  = (unsigned int*)alloc((size_t)NN * 64 * 4);
    unsigned int* hsB_ = (unsigned int*)alloc((size_t)NN * 64 * 4);
    unsigned int* h0p  = (unsigned int*)alloc((size_t)NN * 64 * 4);
    ushort_t* hidB  = (ushort_t*)alloc((size_t)NP * DHID * 2);   // padded
    float*    asv   = (float*)alloc((size_t)NN * 8 * 4);
    float*    adv   = (float*)alloc((size_t)NN * 8 * 4);
    float*    gv    = (float*)alloc((size_t)NN * 16 * 4);
    float*    dinvv = (float*)alloc((size_t)NN * 4);
    float*    stats = (float*)alloc(4 * 256 * 4);
    int*      deg   = (int*)alloc((size_t)NN * 4);
    int*      rowp  = (int*)alloc((size_t)(NN + 1) * 4);
    int*      fill  = (int*)alloc((size_t)NN * 4);
    ushort_t* colv  = (ushort_t*)alloc((size_t)EP * 2);
    int*      part  = (int*)alloc(NB_SCAN * 4);
    int*      poff  = (int*)alloc(NB_SCAN * 4);
    int*      flag  = (int*)alloc(256);
    ushort_t* wtg   = (ushort_t*)alloc((size_t)2 * 128 * 128 * 2);
    ushort_t* wt2   = (ushort_t*)alloc((size_t)2 * 512 * 128 * 2);
    ushort_t* wt3   = (ushort_t*)alloc((size_t)2 * 128 * 512 * 2);
    float* xf   = (float*)alloc((size_t)NN * 2 * 4);
    float* Jf   = (float*)alloc((size_t)NN * 4);
    float* l0wF = (float*)alloc(384 * 4);
    float* l0bF = (float*)alloc(128 * 4);
    float* gwF  = (float*)alloc(32768 * 4);
    float* asF  = (float*)alloc(256 * 4);
    float* adF  = (float*)alloc(256 * 4);
    float* w1F  = (float*)alloc(4096 * 4);
    float* b1gF = (float*)alloc(256 * 4);
    float* b1bF = (float*)alloc(256 * 4);
    float* w2F  = (float*)alloc(131072 * 4);
    float* b2F  = (float*)alloc(1024 * 4);
    float* w3F  = (float*)alloc(131072 * 4);
    float* b3F  = (float*)alloc(256 * 4);
    float* b2gF = (float*)alloc(256 * 4);
    float* b2bF = (float*)alloc(256 * 4);

    // ---- dtype detect + batched canonicalize ----
    k_detect<<<1, 64, 0, stream>>>((const unsigned int*)d_in[1], flag);
    CvtArgs ca;
    {
        const int srcIdx[16] = {0, 1, 3, 4, 5, 6, 7, 8, 9, 10, 11, 12, 13, 14, 15, 16};
        float* dsts[16] = {xf, Jf, l0wF, l0bF, gwF, asF, adF, w1F, b1gF, b1bF,
                           w2F, b2F, w3F, b3F, b2gF, b2bF};
        const int ns[16] = {NN * 2, NN, 384, 128, 32768, 256, 256, 4096, 256, 256,
                            131072, 1024, 131072, 256, 256, 256};
        for (int i = 0; i < 16; ++i) { ca.src[i] = d_in[srcIdx[i]]; ca.dst[i] = dsts[i]; ca.n[i] = ns[i]; }
    }
    k_cvt_all<<<dim3(cdiv(131072, 256), 16), 256, 0, stream>>>(ca, flag);

    // ---- CSR build ----
    hipMemsetAsync(deg, 0, (size_t)NN * 4, stream);
    hipMemsetAsync(stats, 0, 4 * 256 * 4, stream);
    k_deg<<<cdiv(EP, 256), 256, 0, stream>>>(ei, deg);
    k_part<<<NB_SCAN, 256, 0, stream>>>(deg, part);
    k_scan2<<<1, 256, 0, stream>>>(part, poff, rowp);
    k_rowp<<<NB_SCAN, 256, 0, stream>>>(deg, poff, rowp, dinvv, fill);
    k_fill<<<cdiv(EP, 256), 256, 0, stream>>>(ei, fill, colv);

    // ---- batched weight transposes ----
    TrArgs ta;
    {
        const float* srcs[6] = {gwF, gwF + 16384, w2F, w2F + 65536, w3F, w3F + 65536};
        ushort_t* dsts[6] = {wtg, wtg + 16384, wt2, wt2 + 65536, wt3, wt3 + 65536};
        const int Ks[6] = {128, 128, 128, 128, 512, 512};
        const int Ncs[6] = {128, 128, 512, 512, 128, 128};
        for (int i = 0; i < 6; ++i) { ta.src[i] = srcs[i]; ta.dst[i] = dsts[i]; ta.K[i] = Ks[i]; ta.Nc[i] = Ncs[i]; }
    }
    k_tr_all<<<dim3(cdiv(65536, 256), 6), 256, 0, stream>>>(ta);

    // ---- input projection (bf16 h only) ----
    k_lin0<<<cdiv(NN * DEMB, 256), 256, 0, stream>>>(xf, Jf, l0wF, l0bF, hB);

    for (int l = 0; l < 2; ++l) {
        float* st1 = stats + (l * 2 + 0) * 256;
        float* st2 = stats + (l * 2 + 1) * 256;
        ushort_t* zB = xlB;  // reuse xl buffer for z after k_gat is done
        // xl (bf16) = h @ gat_w[l]
        k_gemm64<3><<<dim3(NMT64, 1), 256, 0, stream>>>(hB, wtg + l * 16384, NN, 128, 128,
                                                        nullptr, nullptr, xlB, nullptr);
        k_att<<<cdiv(NN * 8, 256), 256, 0, stream>>>((const unsigned int*)xlB, asF + l * 128,
                                                     adF + l * 128, asv, adv);
        k_gat<<<cdiv(NN * 64, 256), 256, 0, stream>>>(rowp, colv, asv, adv,
                                                      (const unsigned int*)xlB, gv);
        k_z1s<<<512, 256, 0, stream>>>(hB, gv, w1F + l * 2048, st1);
        k_bnapply1<<<cdiv(NN * DEMB, 256), 256, 0, stream>>>(hB, gv, w1F + l * 2048, st1,
                                                             b1gF + l * 128, b1bF + l * 128,
                                                             h1B);
        // hid = relu(h1@W2+b2)
        k_gemm64<1><<<dim3(NMT64, 4), 256, 0, stream>>>(h1B, wt2 + l * 65536, NN, 128, 512,
                                                        b2F + l * 512, nullptr, hidB, nullptr);
        // z = hid@W3 + b3 + h1 (bf16 res), +BN2 stats
        k_gemm64<2><<<dim3(NMT64, 1), 256, 0, stream>>>(hidB, wt3 + l * 65536, NN, 512, 128,
                                                        b3F + l * 128, h1B, zB, st2);
        if (l == 0) {
            k_bnapply<<<cdiv(NN * DEMB, 256), 256, 0, stream>>>(zB, st2, b2gF, b2bF, hB);
        } else {
            k_bnapply_fin<<<cdiv(NN * 64, 256), 256, 0, stream>>>((const unsigned int*)zB, st2,
                                                                  b2gF + 128, b2bF + 128,
                                                                  dinvv, hsA, h0p);
        }
    }

    // ---- APPNP: 10 steps; last writes d_out ----
    unsigned int* pin = hsA;
    unsigned int* pout = hsB_;
    for (int k = 0; k < 10; ++k) {
        int last = (k == 9) ? 1 : 0;
        k_appnp<<<cdiv(NN * 64, 256), 256, 0, stream>>>(rowp, colv, dinvv, pin, h0p, pout,
                                                        Jf, flag, d_out, last);
        unsigned int* tmp = pout;
        pout = pin;
        pin = tmp;
    }
}